// Round 3
// baseline (4935.102 us; speedup 1.0000x reference)
//
#include <hip/hip_runtime.h>
#include <hip/hip_bf16.h>

#define DI __device__ __forceinline__

constexpr int B_ = 256, S_ = 512, I_ = 100, NB_ = 19, H4_ = 400;
constexpr int BOS_ = 17, EOS_ = 18;
constexpr int BS_ = B_ * S_;

DI float sigf(float x) { return 1.0f / (1.0f + __expf(-x)); }
DI float tanhf_(float x) {
  float e = __expf(-2.0f * fabsf(x));
  float r = (1.0f - e) / (1.0f + e);
  return copysignf(r, x);
}

// ---------------------------------------------------------------- prep ----
// M2[19][200] = W2 @ W1 ; c0[19] = W2@b1 + b2 ; biasAll[800] = bih+bhh (f|b)
__global__ __launch_bounds__(256) void prep_kernel(
    const float* __restrict__ W1, const float* __restrict__ b1,
    const float* __restrict__ W2, const float* __restrict__ b2,
    const float* __restrict__ bih_f, const float* __restrict__ bhh_f,
    const float* __restrict__ bih_b, const float* __restrict__ bhh_b,
    float* __restrict__ M2, float* __restrict__ c0, float* __restrict__ biasAll) {
  int t = threadIdx.x;
  for (int c = t; c < 800; c += 256)
    biasAll[c] = (c < 400) ? (bih_f[c] + bhh_f[c]) : (bih_b[c - 400] + bhh_b[c - 400]);
  if (t < 19) {
    float acc = b2[t];
    for (int j = 0; j < 100; ++j) acc += W2[t * 100 + j] * b1[j];
    c0[t] = acc;
  }
  for (int i = t; i < 19 * 200; i += 256) {
    int v = i / 200, d = i - v * 200;
    float acc = 0.f;
    for (int j = 0; j < 100; ++j) acc += W2[v * 100 + j] * W1[j * 200 + d];
    M2[i] = acc;
  }
  for (int i = 3800 + t; i < 4000; i += 256) M2[i] = 0.f;  // pad for float4 loads
}

// ------------------------------------------------------------- pregemm ----
// pre[row][col] = emb[x[row]] . Wih[col] + bias  (gather fused into A-stage)
// tile 64 rows x 80 cols, 256 threads, 4x5 micro-tile, full K=100 in LDS
__global__ __launch_bounds__(256) void pregemm_kernel(
    const int* __restrict__ x, const float* __restrict__ emb,
    const float* __restrict__ Wih_f, const float* __restrict__ Wih_b,
    const float* __restrict__ biasAll,
    float* __restrict__ preF, float* __restrict__ preB) {
  __shared__ __align__(16) float Al[64 * 100];
  __shared__ __align__(16) float Bl[80 * 100];
  __shared__ int xl[64];
  int tid = threadIdx.x;
  int ct = blockIdx.x;  // 0..9
  int rt = blockIdx.y;
  int row0 = rt * 64;
  if (tid < 64) xl[tid] = x[row0 + tid];
  const float* Wsrc = (ct < 5) ? (Wih_f + (size_t)ct * 8000)
                               : (Wih_b + (size_t)(ct - 5) * 8000);
  const float4* bsrc = (const float4*)Wsrc;
  float4* bdst = (float4*)Bl;
  for (int i = tid; i < 2000; i += 256) bdst[i] = bsrc[i];
  __syncthreads();  // xl ready
  float4* adst = (float4*)Al;
  for (int i = tid; i < 1600; i += 256) {
    int r = i / 25, q = i - r * 25;
    adst[i] = ((const float4*)(emb + (size_t)xl[r] * 100))[q];
  }
  __syncthreads();

  int tr = tid >> 4, tc = tid & 15;
  int r0 = tr * 4, c0l = tc * 5;
  float acc[4][5];
#pragma unroll
  for (int i = 0; i < 4; ++i)
#pragma unroll
    for (int j = 0; j < 5; ++j) acc[i][j] = 0.f;

  for (int k = 0; k < 100; k += 4) {
    float4 a[4], b[5];
#pragma unroll
    for (int i = 0; i < 4; ++i) a[i] = *(const float4*)&Al[(r0 + i) * 100 + k];
#pragma unroll
    for (int j = 0; j < 5; ++j) b[j] = *(const float4*)&Bl[(c0l + j) * 100 + k];
#pragma unroll
    for (int i = 0; i < 4; ++i)
#pragma unroll
      for (int j = 0; j < 5; ++j) {
        acc[i][j] += a[i].x * b[j].x;
        acc[i][j] += a[i].y * b[j].y;
        acc[i][j] += a[i].z * b[j].z;
        acc[i][j] += a[i].w * b[j].w;
      }
  }

  float* dst = (ct < 5) ? preF : preB;
  int colbase = (ct < 5) ? (ct * 80 + c0l) : ((ct - 5) * 80 + c0l);
#pragma unroll
  for (int i = 0; i < 4; ++i)
#pragma unroll
    for (int j = 0; j < 5; ++j)
      dst[(size_t)(row0 + r0 + i) * 400 + colbase + j] =
          acc[i][j] + biasAll[ct * 80 + c0l + j];
}

// ---------------------------------------------------------------- scan ----
// one block (128 thr, 100 active) per (seq, dir) in the chunk; thread j owns
// all 4 gate rows of unit j (Whh rows {j,100+j,200+j,300+j} in 400 VGPRs).
// h broadcast via double-buffered LDS, ONE barrier/step, activations fused.
// hout may ALIAS pre (h[s] written into consumed pre slot) -> no __restrict__.
__global__ __launch_bounds__(128, 1) void scan_kernel(
    const float* preF, const float* preB,
    const float* __restrict__ Whh_f, const float* __restrict__ Whh_b,
    float* hfC, float* hbC, int hStride) {
  __shared__ __align__(16) float h_lds[2][104];
  int bid = blockIdx.x;
  int b = bid >> 1, dir = bid & 1;
  int j = threadIdx.x;
  const float* pre = (dir ? preB : preF) + (size_t)b * 512 * 400;
  float* hout = (dir ? hbC : hfC) + (size_t)b * 512 * hStride;
  const float* Whh = dir ? Whh_b : Whh_f;

  float4 w0[25], w1[25], w2[25], w3[25];
  if (j < 100) {
    const float4* s0 = (const float4*)(Whh + (size_t)j * 100);
    const float4* s1 = (const float4*)(Whh + (size_t)(100 + j) * 100);
    const float4* s2 = (const float4*)(Whh + (size_t)(200 + j) * 100);
    const float4* s3 = (const float4*)(Whh + (size_t)(300 + j) * 100);
#pragma unroll
    for (int kk = 0; kk < 25; ++kk) {
      w0[kk] = s0[kk]; w1[kk] = s1[kk]; w2[kk] = s2[kk]; w3[kk] = s3[kk];
    }
    h_lds[0][j] = 0.f;
  }
  float c = 0.f;
  __syncthreads();

  float4 p = {0.f, 0.f, 0.f, 0.f};
  if (j < 100) {
    const float* pp = pre + (size_t)(dir ? 511 : 0) * 400 + j;
    p.x = pp[0]; p.y = pp[100]; p.z = pp[200]; p.w = pp[300];
  }

  for (int t = 0; t < 512; ++t) {
    int s = dir ? (511 - t) : t;
    float4 pn = {0.f, 0.f, 0.f, 0.f};
    if (j < 100) {
      if (t < 511) {  // prefetch next step's slot (never the one written below)
        int sn = dir ? (510 - t) : (t + 1);
        const float* pp = pre + (size_t)sn * 400 + j;
        pn.x = pp[0]; pn.y = pp[100]; pn.z = pp[200]; pn.w = pp[300];
      }
      float ai = p.x, af = p.y, ag = p.z, ao = p.w;
      const float* hb_ = h_lds[t & 1];
#pragma unroll
      for (int kk = 0; kk < 25; ++kk) {
        float4 h4 = *(const float4*)&hb_[kk * 4];
        ai += w0[kk].x * h4.x + w0[kk].y * h4.y + w0[kk].z * h4.z + w0[kk].w * h4.w;
        af += w1[kk].x * h4.x + w1[kk].y * h4.y + w1[kk].z * h4.z + w1[kk].w * h4.w;
        ag += w2[kk].x * h4.x + w2[kk].y * h4.y + w2[kk].z * h4.z + w2[kk].w * h4.w;
        ao += w3[kk].x * h4.x + w3[kk].y * h4.y + w3[kk].z * h4.z + w3[kk].w * h4.w;
      }
      c = sigf(af) * c + sigf(ai) * tanhf_(ag);
      float h = sigf(ao) * tanhf_(c);
      h_lds[(t + 1) & 1][j] = h;
      hout[(size_t)s * hStride + j] = h;
    }
    __syncthreads();
    p = pn;
  }
}

// ---------------------------------------------------------------- emis ----
// em[row][v] = sum_d hcat[row][d] * M2[v][d] + c0[v]; 32 rows/block (<64KB LDS)
__global__ __launch_bounds__(128) void emis_kernel(
    const float* __restrict__ hfB, const float* __restrict__ hbB, int hStride,
    const float* __restrict__ M2g, const float* __restrict__ c0g,
    float* __restrict__ em) {
  __shared__ __align__(16) float hrow[32 * 204];
  __shared__ __align__(16) float M2l[4000];
  __shared__ float c0l[20];
  int tid = threadIdx.x;
  int row0 = blockIdx.x * 32;
  for (int i = tid; i < 800; i += 128) {
    int r = i / 25, q = i - r * 25;
    *(float4*)&hrow[r * 204 + q * 4] =
        *(const float4*)(hfB + (size_t)(row0 + r) * hStride + q * 4);
    *(float4*)&hrow[r * 204 + 100 + q * 4] =
        *(const float4*)(hbB + (size_t)(row0 + r) * hStride + q * 4);
  }
  for (int i = tid; i < 1000; i += 128) ((float4*)M2l)[i] = ((const float4*)M2g)[i];
  if (tid < 20) c0l[tid] = (tid < 19) ? c0g[tid] : 0.f;
  __syncthreads();

  int r = tid >> 2, q = tid & 3;
  int v0 = q * 5;
  float acc[5] = {0.f, 0.f, 0.f, 0.f, 0.f};
  for (int k = 0; k < 200; k += 4) {
    float4 h4 = *(const float4*)&hrow[r * 204 + k];
#pragma unroll
    for (int i = 0; i < 5; ++i) {
      float4 m4 = *(const float4*)&M2l[(v0 + i) * 200 + k];
      acc[i] += h4.x * m4.x + h4.y * m4.y + h4.z * m4.z + h4.w * m4.w;
    }
  }
  int nv = (q == 3) ? 4 : 5;
  for (int i = 0; i < nv; ++i)
    em[(size_t)(row0 + r) * 19 + v0 + i] = acc[i] + c0l[v0 + i];
}

// ----------------------------------------------------------------- crf ----
// one wave per batch element; log2 domain (native v_exp/v_log). BOS col and
// EOS row are annihilated by the -10000 mask (exp underflows to 0 in fp32
// exactly as in the reference), so the live recursion is 17x17.
__global__ __launch_bounds__(64) void crf_kernel(
    const float* __restrict__ em, const int* __restrict__ target,
    const float* __restrict__ T, float* __restrict__ res) {
  __shared__ float em_l[512 * 19];
  __shared__ float T_l[361];
  __shared__ int tgt_l[512];
  __shared__ float a_lds[2][20];
  constexpr float LOG2E = 1.4426950408889634f;
  constexpr float LN2 = 0.6931471805599453f;
  int b = blockIdx.x, lane = threadIdx.x;
  const float* emsrc = em + (size_t)b * 512 * 19;
  for (int i = lane; i < 512 * 19; i += 64) em_l[i] = emsrc[i] * LOG2E;
  for (int i = lane; i < 361; i += 64) T_l[i] = T[i] * LOG2E;
  for (int i = lane; i < 512; i += 64) tgt_l[i] = target[b * 512 + i];
  __syncthreads();

  float sc = 0.f;
  for (int t = lane; t < 512; t += 64) {
    int tg = tgt_l[t];
    sc += em_l[t * 19 + tg];
    if (t < 511) sc += T_l[tg * 19 + tgt_l[t + 1]];
  }
#pragma unroll
  for (int off = 32; off >= 1; off >>= 1) sc += __shfl_xor(sc, off);

  int v = (lane < 17) ? lane : 0;
  float Tcol[17];
#pragma unroll
  for (int u = 0; u < 17; ++u) Tcol[u] = T_l[u * 19 + v];
  float a[17];
#pragma unroll
  for (int u = 0; u < 17; ++u) a[u] = T_l[BOS_ * 19 + u] + em_l[u];

  for (int t = 1; t < 512; ++t) {
    float xx[17];
#pragma unroll
    for (int u = 0; u < 17; ++u) xx[u] = a[u] + Tcol[u];
    float m = xx[0];
#pragma unroll
    for (int u = 1; u < 17; ++u) m = fmaxf(m, xx[u]);
    float s0 = 0.f, s1 = 0.f, s2 = 0.f, s3 = 0.f;
#pragma unroll
    for (int u = 0; u < 16; u += 4) {
      s0 += exp2f(xx[u] - m);
      s1 += exp2f(xx[u + 1] - m);
      s2 += exp2f(xx[u + 2] - m);
      s3 += exp2f(xx[u + 3] - m);
    }
    s0 += exp2f(xx[16] - m);
    float na = m + log2f((s0 + s1) + (s2 + s3)) + em_l[t * 19 + v];
    int wb = t & 1;
    if (lane < 17) a_lds[wb][lane] = na;
    __syncthreads();
#pragma unroll
    for (int u = 0; u < 17; ++u) a[u] = a_lds[wb][u];
  }

  float xx[17];
#pragma unroll
  for (int u = 0; u < 17; ++u) xx[u] = a[u] + T_l[u * 19 + EOS_];
  float m = xx[0];
#pragma unroll
  for (int u = 1; u < 17; ++u) m = fmaxf(m, xx[u]);
  float ssum = 0.f;
#pragma unroll
  for (int u = 0; u < 17; ++u) ssum += exp2f(xx[u] - m);
  float part = m + log2f(ssum);

  if (lane == 0) {
    float score = sc + T_l[BOS_ * 19 + tgt_l[0]] + T_l[tgt_l[511] * 19 + EOS_];
    res[b] = (score - part) * LN2;
  }
}

// ------------------------------------------------------------- final -----
__global__ void final_kernel(const float* __restrict__ res, float* __restrict__ out) {
  int lane = threadIdx.x;
  float s = 0.f;
  for (int i = lane; i < 256; i += 64) s += res[i];
#pragma unroll
  for (int off = 32; off >= 1; off >>= 1) s += __shfl_xor(s, off);
  if (lane == 0) out[0] = -s * (1.0f / 256.0f);
}

// ---------------------------------------------------------------------------
extern "C" void kernel_launch(void* const* d_in, const int* in_sizes, int n_in,
                              void* d_out, int out_size, void* d_ws, size_t ws_size,
                              hipStream_t stream) {
  const int*   x      = (const int*)d_in[0];
  const int*   target = (const int*)d_in[1];
  const float* emb    = (const float*)d_in[2];
  const float* Wih_f  = (const float*)d_in[3];
  const float* Whh_f  = (const float*)d_in[4];
  const float* Wih_b  = (const float*)d_in[7];
  const float* Whh_b  = (const float*)d_in[8];
  const float* bih_f  = (const float*)d_in[5];
  const float* bhh_f  = (const float*)d_in[6];
  const float* bih_b  = (const float*)d_in[9];
  const float* bhh_b  = (const float*)d_in[10];
  const float* W1     = (const float*)d_in[11];
  const float* b1     = (const float*)d_in[12];
  const float* W2     = (const float*)d_in[13];
  const float* b2     = (const float*)d_in[14];
  const float* trans  = (const float*)d_in[15];
  float* out = (float*)d_out;

  float* ws = (float*)d_ws;
  // fixed small region first
  float* em      = ws;                          // BS*19
  float* M2      = em + (size_t)BS_ * 19;       // 4000
  float* c0      = M2 + 4000;                   // 64
  float* biasAll = c0 + 64;                     // 1024
  float* res     = biasAll + 1024;              // 256
  float* big     = res + 256;

  // choose chunking to fit ws_size (ws_size is constant across calls ->
  // identical work every call, graph-capture safe)
  size_t wsf = ws_size / sizeof(float);
  size_t fixed = (size_t)BS_ * 19 + 8192;
  int NCH = 16;
  if (fixed + (size_t)BS_ * 800 <= wsf) NCH = 1;                       // 431 MB, h aliased
  else if (fixed + (size_t)BS_ * 400 + (size_t)BS_ * 200 <= wsf) NCH = 2;
  else if (fixed + (size_t)BS_ * 200 + (size_t)BS_ * 200 <= wsf) NCH = 4;
  else if (fixed + (size_t)BS_ * 100 + (size_t)BS_ * 200 <= wsf) NCH = 8;

  int CB = B_ / NCH;                       // sequences per chunk
  size_t preSz = (size_t)CB * 512 * 400;   // floats per direction
  float* preF = big;
  float* preB = big + preSz;
  float* hfP; float* hbP; int hStride;
  if (NCH == 1) { hfP = preF; hbP = preB; hStride = 400; }
  else { hfP = preB + preSz; hbP = hfP + (size_t)BS_ * 100; hStride = 100; }

  prep_kernel<<<1, 256, 0, stream>>>(W1, b1, W2, b2, bih_f, bhh_f, bih_b, bhh_b,
                                     M2, c0, biasAll);
  for (int c = 0; c < NCH; ++c) {
    const int* xc = x + (size_t)c * CB * 512;
    pregemm_kernel<<<dim3(10, CB * 8), 256, 0, stream>>>(xc, emb, Wih_f, Wih_b,
                                                         biasAll, preF, preB);
    float* hfC = (NCH == 1) ? preF : hfP + (size_t)c * CB * 512 * 100;
    float* hbC = (NCH == 1) ? preB : hbP + (size_t)c * CB * 512 * 100;
    scan_kernel<<<CB * 2, 128, 0, stream>>>(preF, preB, Whh_f, Whh_b,
                                            hfC, hbC, hStride);
  }
  emis_kernel<<<BS_ / 32, 128, 0, stream>>>(hfP, hbP, hStride, M2, c0, em);
  crf_kernel<<<B_, 64, 0, stream>>>(em, target, trans, res);
  final_kernel<<<1, 64, 0, stream>>>(res, out);
}

// Round 5
// 2166.786 us; speedup vs baseline: 2.2776x; 2.2776x over previous
//
#include <hip/hip_runtime.h>
#include <hip/hip_bf16.h>

#define DI __device__ __forceinline__

constexpr int B_ = 256, S_ = 512, I_ = 100, NB_ = 19, H4_ = 400;
constexpr int BOS_ = 17, EOS_ = 18;
constexpr int BS_ = B_ * S_;

DI float sigf(float x) { return 1.0f / (1.0f + __expf(-x)); }
DI float tanhf_(float x) {
  float e = __expf(-2.0f * fabsf(x));
  float r = (1.0f - e) / (1.0f + e);
  return copysignf(r, x);
}

// quad (4-lane) sum via DPP quad_perm: lanes 4k..4k+3 all end with the sum
DI float qred(float a) {
  a += __int_as_float(__builtin_amdgcn_mov_dpp(__float_as_int(a), 0xB1, 0xF, 0xF, true));
  a += __int_as_float(__builtin_amdgcn_mov_dpp(__float_as_int(a), 0x4E, 0xF, 0xF, true));
  return a;
}

// ---------------------------------------------------------------- prep ----
// M2[19][200] = W2 @ W1 ; c0[19] = W2@b1 + b2 ; biasAll[800] = bih+bhh (f|b)
__global__ __launch_bounds__(256) void prep_kernel(
    const float* __restrict__ W1, const float* __restrict__ b1,
    const float* __restrict__ W2, const float* __restrict__ b2,
    const float* __restrict__ bih_f, const float* __restrict__ bhh_f,
    const float* __restrict__ bih_b, const float* __restrict__ bhh_b,
    float* __restrict__ M2, float* __restrict__ c0, float* __restrict__ biasAll) {
  int t = threadIdx.x;
  for (int c = t; c < 800; c += 256)
    biasAll[c] = (c < 400) ? (bih_f[c] + bhh_f[c]) : (bih_b[c - 400] + bhh_b[c - 400]);
  if (t < 19) {
    float acc = b2[t];
    for (int j = 0; j < 100; ++j) acc += W2[t * 100 + j] * b1[j];
    c0[t] = acc;
  }
  for (int i = t; i < 19 * 200; i += 256) {
    int v = i / 200, d = i - v * 200;
    float acc = 0.f;
    for (int j = 0; j < 100; ++j) acc += W2[v * 100 + j] * W1[j * 200 + d];
    M2[i] = acc;
  }
  for (int i = 3800 + t; i < 4000; i += 256) M2[i] = 0.f;  // pad for float4 loads
}

// ---------------------------------------------------------------- scan ----
// Fused input-GEMV + LSTM scan. One block (400 thr) per (seq, dir).
// Thread (u = tid>>2, q = tid&3) owns quarter q (25 cols) of the 4 gate rows
// {u, 100+u, 200+u, 300+u} of BOTH Whh and Wih (200 VGPRs of weights).
// Per step: 8 quarter-dots (4 recurrence from h_lds, 4 input-gemv from xe_lds,
// one step ahead), DPP quad-reduce; lane q==0 applies activations. The gemv
// result stays in the exact lane that consumes it next step - no pre buffer
// in memory at all. Double-buffered h/xe in LDS, ONE barrier per step.
__global__ __launch_bounds__(400, 2) void scan_fused_kernel(
    const int* __restrict__ x, const float* __restrict__ emb,
    const float* __restrict__ Wih_f, const float* __restrict__ Wih_b,
    const float* __restrict__ Whh_f, const float* __restrict__ Whh_b,
    const float* __restrict__ biasAll,
    float* __restrict__ hf, float* __restrict__ hb) {
  __shared__ __align__(16) float h_q[2][4][32];   // [buf][quarter][25 used]
  __shared__ __align__(16) float xe_q[2][4][32];
  int bid = blockIdx.x;
  int b = bid >> 1, dir = bid & 1;
  int tid = threadIdx.x;
  int u = tid >> 2, q = tid & 3;
  const float* Whh = dir ? Whh_b : Whh_f;
  const float* Wih = dir ? Wih_b : Wih_f;
  float* hout = (dir ? hb : hf) + (size_t)b * 512 * 100;
  const int* xb = x + (size_t)b * 512;
  const int s0 = dir ? 511 : 0, sstep = dir ? -1 : 1;

  // ---- weight fragments (scalar loads: rows are not 16B-aligned per quarter)
  float4 wr4[4][6], wi4[4][6];
  float wrt[4], wit[4], bias[4];
#pragma unroll
  for (int g = 0; g < 4; ++g) {
    const float* pr = Whh + (size_t)(g * 100 + u) * 100 + q * 25;
    const float* pi = Wih + (size_t)(g * 100 + u) * 100 + q * 25;
#pragma unroll
    for (int k = 0; k < 6; ++k) {
      wr4[g][k] = make_float4(pr[4 * k], pr[4 * k + 1], pr[4 * k + 2], pr[4 * k + 3]);
      wi4[g][k] = make_float4(pi[4 * k], pi[4 * k + 1], pi[4 * k + 2], pi[4 * k + 3]);
    }
    wrt[g] = pr[24];
    wit[g] = pi[24];
    bias[g] = biasAll[dir * 400 + g * 100 + u];
  }
  const int qq_u = u / 25, pp_u = u - (u / 25) * 25;
  int xq0 = 0, xp0 = 0;
  if (tid < 100) { xq0 = tid / 25; xp0 = tid - (tid / 25) * 25; }

  // ---- prologue: xe[s0] -> xe_q[0]; h_q[0] = 0
  if (tid < 100) xe_q[0][xq0][xp0] = emb[(size_t)xb[s0] * 100 + tid];
  if (tid < 128) ((float*)h_q[0])[tid] = 0.f;
  __syncthreads();

  // gemv0: p = Wih @ xe[s0]  (consumed by step 0's activation)
  float p[4];
  {
    const float* xq = &xe_q[0][q][0];
    float xt = xq[24];
    float e0 = wit[0] * xt, e1 = wit[1] * xt, e2 = wit[2] * xt, e3 = wit[3] * xt;
#pragma unroll
    for (int k = 0; k < 6; ++k) {
      float4 xv = *(const float4*)(xq + 4 * k);
      e0 += wi4[0][k].x * xv.x + wi4[0][k].y * xv.y + wi4[0][k].z * xv.z + wi4[0][k].w * xv.w;
      e1 += wi4[1][k].x * xv.x + wi4[1][k].y * xv.y + wi4[1][k].z * xv.z + wi4[1][k].w * xv.w;
      e2 += wi4[2][k].x * xv.x + wi4[2][k].y * xv.y + wi4[2][k].z * xv.z + wi4[2][k].w * xv.w;
      e3 += wi4[3][k].x * xv.x + wi4[3][k].y * xv.y + wi4[3][k].z * xv.z + wi4[3][k].w * xv.w;
    }
    p[0] = qred(e0); p[1] = qred(e1); p[2] = qred(e2); p[3] = qred(e3);
  }

  // stage xe[s0+sstep] -> xe_q[1]; prime the x-index pipeline (2 ahead)
  if (tid < 100) xe_q[1][xq0][xp0] = emb[(size_t)xb[s0 + sstep] * 100 + tid];
  int xidx = xb[min(511, max(0, s0 + 2 * sstep))];
  __syncthreads();

  float c = 0.f;
  for (int t = 0; t < 512; ++t) {
    int s = s0 + sstep * t;
    // prefetch emb row for step t+2 (staged at step end), x-index for t+3
    float v = 0.f;
    if (tid < 100) v = emb[(size_t)xidx * 100 + tid];
    xidx = xb[min(511, max(0, s + 3 * sstep))];

    const float* hq = &h_q[t & 1][q][0];
    const float* xq = &xe_q[(t + 1) & 1][q][0];
    float ht = hq[24], xt = xq[24];
    float r0 = wrt[0] * ht, r1 = wrt[1] * ht, r2 = wrt[2] * ht, r3 = wrt[3] * ht;
    float e0 = wit[0] * xt, e1 = wit[1] * xt, e2 = wit[2] * xt, e3 = wit[3] * xt;
#pragma unroll
    for (int k = 0; k < 6; ++k) {
      float4 hv = *(const float4*)(hq + 4 * k);
      float4 xv = *(const float4*)(xq + 4 * k);
      r0 += wr4[0][k].x * hv.x + wr4[0][k].y * hv.y + wr4[0][k].z * hv.z + wr4[0][k].w * hv.w;
      r1 += wr4[1][k].x * hv.x + wr4[1][k].y * hv.y + wr4[1][k].z * hv.z + wr4[1][k].w * hv.w;
      r2 += wr4[2][k].x * hv.x + wr4[2][k].y * hv.y + wr4[2][k].z * hv.z + wr4[2][k].w * hv.w;
      r3 += wr4[3][k].x * hv.x + wr4[3][k].y * hv.y + wr4[3][k].z * hv.z + wr4[3][k].w * hv.w;
      e0 += wi4[0][k].x * xv.x + wi4[0][k].y * xv.y + wi4[0][k].z * xv.z + wi4[0][k].w * xv.w;
      e1 += wi4[1][k].x * xv.x + wi4[1][k].y * xv.y + wi4[1][k].z * xv.z + wi4[1][k].w * xv.w;
      e2 += wi4[2][k].x * xv.x + wi4[2][k].y * xv.y + wi4[2][k].z * xv.z + wi4[2][k].w * xv.w;
      e3 += wi4[3][k].x * xv.x + wi4[3][k].y * xv.y + wi4[3][k].z * xv.z + wi4[3][k].w * xv.w;
    }
    r0 = qred(r0); r1 = qred(r1); r2 = qred(r2); r3 = qred(r3);
    e0 = qred(e0); e1 = qred(e1); e2 = qred(e2); e3 = qred(e3);

    if (q == 0) {
      float gi = r0 + p[0] + bias[0];
      float gf = r1 + p[1] + bias[1];
      float gg = r2 + p[2] + bias[2];
      float go = r3 + p[3] + bias[3];
      c = sigf(gf) * c + sigf(gi) * tanhf_(gg);
      float h = sigf(go) * tanhf_(c);
      h_q[(t + 1) & 1][qq_u][pp_u] = h;
      hout[(size_t)s * 100 + u] = h;
    }
    p[0] = e0; p[1] = e1; p[2] = e2; p[3] = e3;
    if (tid < 100) xe_q[t & 1][xq0][xp0] = v;  // xe row s+2*sstep, read at t+2
    __syncthreads();
  }
}

// ---------------------------------------------------------------- emis ----
// em[row][v] = sum_d hcat[row][d] * M2[v][d] + c0[v]; 32 rows/block
__global__ __launch_bounds__(128) void emis_kernel(
    const float* __restrict__ hfB, const float* __restrict__ hbB,
    const float* __restrict__ M2g, const float* __restrict__ c0g,
    float* __restrict__ em) {
  __shared__ __align__(16) float hrow[32 * 204];
  __shared__ __align__(16) float M2l[4000];
  __shared__ float c0l[20];
  int tid = threadIdx.x;
  int row0 = blockIdx.x * 32;
  for (int i = tid; i < 800; i += 128) {
    int r = i / 25, q = i - r * 25;
    *(float4*)&hrow[r * 204 + q * 4] =
        *(const float4*)(hfB + (size_t)(row0 + r) * 100 + q * 4);
    *(float4*)&hrow[r * 204 + 100 + q * 4] =
        *(const float4*)(hbB + (size_t)(row0 + r) * 100 + q * 4);
  }
  for (int i = tid; i < 1000; i += 128) ((float4*)M2l)[i] = ((const float4*)M2g)[i];
  if (tid < 20) c0l[tid] = (tid < 19) ? c0g[tid] : 0.f;
  __syncthreads();

  int r = tid >> 2, q = tid & 3;
  int v0 = q * 5;
  float acc[5] = {0.f, 0.f, 0.f, 0.f, 0.f};
  for (int k = 0; k < 200; k += 4) {
    float4 h4 = *(const float4*)&hrow[r * 204 + k];
#pragma unroll
    for (int i = 0; i < 5; ++i) {
      float4 m4 = *(const float4*)&M2l[(v0 + i) * 200 + k];
      acc[i] += h4.x * m4.x + h4.y * m4.y + h4.z * m4.z + h4.w * m4.w;
    }
  }
  int nv = (q == 3) ? 4 : 5;
  for (int i = 0; i < nv; ++i)
    em[(size_t)(row0 + r) * 19 + v0 + i] = acc[i] + c0l[v0 + i];
}

// ----------------------------------------------------------------- crf ----
// one wave per batch element; log2 domain (native v_exp/v_log). BOS col and
// EOS row are annihilated by the -10000 mask (exp underflows to 0 in fp32
// exactly as in the reference), so the live recursion is 17x17.
__global__ __launch_bounds__(64) void crf_kernel(
    const float* __restrict__ em, const int* __restrict__ target,
    const float* __restrict__ T, float* __restrict__ res) {
  __shared__ float em_l[512 * 19];
  __shared__ float T_l[361];
  __shared__ int tgt_l[512];
  __shared__ float a_lds[2][20];
  constexpr float LOG2E = 1.4426950408889634f;
  constexpr float LN2 = 0.6931471805599453f;
  int b = blockIdx.x, lane = threadIdx.x;
  const float* emsrc = em + (size_t)b * 512 * 19;
  for (int i = lane; i < 512 * 19; i += 64) em_l[i] = emsrc[i] * LOG2E;
  for (int i = lane; i < 361; i += 64) T_l[i] = T[i] * LOG2E;
  for (int i = lane; i < 512; i += 64) tgt_l[i] = target[b * 512 + i];
  __syncthreads();

  float sc = 0.f;
  for (int t = lane; t < 512; t += 64) {
    int tg = tgt_l[t];
    sc += em_l[t * 19 + tg];
    if (t < 511) sc += T_l[tg * 19 + tgt_l[t + 1]];
  }
#pragma unroll
  for (int off = 32; off >= 1; off >>= 1) sc += __shfl_xor(sc, off);

  int v = (lane < 17) ? lane : 0;
  float Tcol[17];
#pragma unroll
  for (int u = 0; u < 17; ++u) Tcol[u] = T_l[u * 19 + v];
  float a[17];
#pragma unroll
  for (int u = 0; u < 17; ++u) a[u] = T_l[BOS_ * 19 + u] + em_l[u];

  for (int t = 1; t < 512; ++t) {
    float xx[17];
#pragma unroll
    for (int u = 0; u < 17; ++u) xx[u] = a[u] + Tcol[u];
    float m = xx[0];
#pragma unroll
    for (int u = 1; u < 17; ++u) m = fmaxf(m, xx[u]);
    float s0 = 0.f, s1 = 0.f, s2 = 0.f, s3 = 0.f;
#pragma unroll
    for (int u = 0; u < 16; u += 4) {
      s0 += exp2f(xx[u] - m);
      s1 += exp2f(xx[u + 1] - m);
      s2 += exp2f(xx[u + 2] - m);
      s3 += exp2f(xx[u + 3] - m);
    }
    s0 += exp2f(xx[16] - m);
    float na = m + log2f((s0 + s1) + (s2 + s3)) + em_l[t * 19 + v];
    int wb = t & 1;
    if (lane < 17) a_lds[wb][lane] = na;
    __syncthreads();
#pragma unroll
    for (int u = 0; u < 17; ++u) a[u] = a_lds[wb][u];
  }

  float xx[17];
#pragma unroll
  for (int u = 0; u < 17; ++u) xx[u] = a[u] + T_l[u * 19 + EOS_];
  float m = xx[0];
#pragma unroll
  for (int u = 1; u < 17; ++u) m = fmaxf(m, xx[u]);
  float ssum = 0.f;
#pragma unroll
  for (int u = 0; u < 17; ++u) ssum += exp2f(xx[u] - m);
  float part = m + log2f(ssum);

  if (lane == 0) {
    float score = sc + T_l[BOS_ * 19 + tgt_l[0]] + T_l[tgt_l[511] * 19 + EOS_];
    res[b] = (score - part) * LN2;
  }
}

// ------------------------------------------------------------- final -----
__global__ void final_kernel(const float* __restrict__ res, float* __restrict__ out) {
  int lane = threadIdx.x;
  float s = 0.f;
  for (int i = lane; i < 256; i += 64) s += res[i];
#pragma unroll
  for (int off = 32; off >= 1; off >>= 1) s += __shfl_xor(s, off);
  if (lane == 0) out[0] = -s * (1.0f / 256.0f);
}

// ---------------------------------------------------------------------------
extern "C" void kernel_launch(void* const* d_in, const int* in_sizes, int n_in,
                              void* d_out, int out_size, void* d_ws, size_t ws_size,
                              hipStream_t stream) {
  const int*   x      = (const int*)d_in[0];
  const int*   target = (const int*)d_in[1];
  const float* emb    = (const float*)d_in[2];
  const float* Wih_f  = (const float*)d_in[3];
  const float* Whh_f  = (const float*)d_in[4];
  const float* bih_f  = (const float*)d_in[5];
  const float* bhh_f  = (const float*)d_in[6];
  const float* Wih_b  = (const float*)d_in[7];
  const float* Whh_b  = (const float*)d_in[8];
  const float* bih_b  = (const float*)d_in[9];
  const float* bhh_b  = (const float*)d_in[10];
  const float* W1     = (const float*)d_in[11];
  const float* b1     = (const float*)d_in[12];
  const float* W2     = (const float*)d_in[13];
  const float* b2     = (const float*)d_in[14];
  const float* trans  = (const float*)d_in[15];
  float* out = (float*)d_out;

  float* ws = (float*)d_ws;
  float* em      = ws;                          // BS*19
  float* M2      = em + (size_t)BS_ * 19;       // 4000
  float* c0      = M2 + 4000;                   // 64
  float* biasAll = c0 + 64;                     // 1024
  float* res     = biasAll + 1024;              // 256
  float* hfbuf   = res + 256;                   // BS*100
  float* hbbuf   = hfbuf + (size_t)BS_ * 100;   // BS*100  (total ~115 MB)

  prep_kernel<<<1, 256, 0, stream>>>(W1, b1, W2, b2, bih_f, bhh_f, bih_b, bhh_b,
                                     M2, c0, biasAll);
  scan_fused_kernel<<<512, 400, 0, stream>>>(x, emb, Wih_f, Wih_b, Whh_f, Whh_b,
                                             biasAll, hfbuf, hbbuf);
  emis_kernel<<<BS_ / 32, 128, 0, stream>>>(hfbuf, hbbuf, M2, c0, em);
  crf_kernel<<<B_, 64, 0, stream>>>(em, target, trans, res);
  final_kernel<<<1, 64, 0, stream>>>(res, out);
}

// Round 6
// 2022.068 us; speedup vs baseline: 2.4406x; 1.0716x over previous
//
#include <hip/hip_runtime.h>
#include <hip/hip_bf16.h>

#define DI __device__ __forceinline__

constexpr int B_ = 256, S_ = 512, I_ = 100, NB_ = 19, H4_ = 400;
constexpr int BOS_ = 17, EOS_ = 18;
constexpr int BS_ = B_ * S_;

DI float sigf(float x) { return 1.0f / (1.0f + __expf(-x)); }
DI float tanhf_(float x) {
  float e = __expf(-2.0f * fabsf(x));
  float r = (1.0f - e) / (1.0f + e);
  return copysignf(r, x);
}

// quad (4-lane) sum via DPP quad_perm: lanes 4k..4k+3 all end with the sum
DI float qred(float a) {
  a += __int_as_float(__builtin_amdgcn_mov_dpp(__float_as_int(a), 0xB1, 0xF, 0xF, true));
  a += __int_as_float(__builtin_amdgcn_mov_dpp(__float_as_int(a), 0x4E, 0xF, 0xF, true));
  return a;
}

// ---------------------------------------------------------------- prep ----
// M2[19][200] = W2 @ W1 ; c0[19] = W2@b1 + b2 ; biasAll[800] = bih+bhh (f|b)
__global__ __launch_bounds__(256) void prep_kernel(
    const float* __restrict__ W1, const float* __restrict__ b1,
    const float* __restrict__ W2, const float* __restrict__ b2,
    const float* __restrict__ bih_f, const float* __restrict__ bhh_f,
    const float* __restrict__ bih_b, const float* __restrict__ bhh_b,
    float* __restrict__ M2, float* __restrict__ c0, float* __restrict__ biasAll) {
  int t = threadIdx.x;
  for (int c = t; c < 800; c += 256)
    biasAll[c] = (c < 400) ? (bih_f[c] + bhh_f[c]) : (bih_b[c - 400] + bhh_b[c - 400]);
  if (t < 19) {
    float acc = b2[t];
    for (int j = 0; j < 100; ++j) acc += W2[t * 100 + j] * b1[j];
    c0[t] = acc;
  }
  for (int i = t; i < 19 * 200; i += 256) {
    int v = i / 200, d = i - v * 200;
    float acc = 0.f;
    for (int j = 0; j < 100; ++j) acc += W2[v * 100 + j] * W1[j * 200 + d];
    M2[i] = acc;
  }
  for (int i = 3800 + t; i < 4000; i += 256) M2[i] = 0.f;  // pad for float4 loads
}

// ---------------------------------------------------------------- scan ----
// Fused input-GEMV + LSTM scan. One block (400 thr) per (seq, dir).
// Thread (u = tid>>2, q = tid&3) owns quarter q (25 cols) of the 4 gate rows
// {u, 100+u, 200+u, 300+u} of BOTH Whh and Wih (~204 VGPRs of weights).
// LDS layout [4][28]: quarter bases {0,28,24,20} mod 32 banks -> b128 reads
// across the 4 quarters hit disjoint banks (was 4-way conflict at stride 32).
// launch_bounds(400,1): 256-VGPR cap (2 waves/SIMD) so weights stay in arch
// VGPRs (no accvgpr round-trips, no scratch spill).
__global__ __launch_bounds__(400, 1) void scan_fused_kernel(
    const int* __restrict__ x, const float* __restrict__ emb,
    const float* __restrict__ Wih_f, const float* __restrict__ Wih_b,
    const float* __restrict__ Whh_f, const float* __restrict__ Whh_b,
    const float* __restrict__ biasAll,
    float* __restrict__ hf, float* __restrict__ hb) {
  __shared__ __align__(16) float h_q[2][4][28];   // [buf][quarter][25 used]
  __shared__ __align__(16) float xe_q[2][4][28];
  int bid = blockIdx.x;
  int b = bid >> 1, dir = bid & 1;
  int tid = threadIdx.x;
  int u = tid >> 2, q = tid & 3;
  const float* Whh = dir ? Whh_b : Whh_f;
  const float* Wih = dir ? Wih_b : Wih_f;
  float* hout = (dir ? hb : hf) + (size_t)b * 512 * 100;
  const int* xb = x + (size_t)b * 512;
  const int s0 = dir ? 511 : 0, sstep = dir ? -1 : 1;

  // ---- weight fragments (scalar loads: quarter rows aren't 16B-aligned)
  float4 wr4[4][6], wi4[4][6];
  float wrt[4], wit[4], bias[4];
#pragma unroll
  for (int g = 0; g < 4; ++g) {
    const float* pr = Whh + (size_t)(g * 100 + u) * 100 + q * 25;
    const float* pi = Wih + (size_t)(g * 100 + u) * 100 + q * 25;
#pragma unroll
    for (int k = 0; k < 6; ++k) {
      wr4[g][k] = make_float4(pr[4 * k], pr[4 * k + 1], pr[4 * k + 2], pr[4 * k + 3]);
      wi4[g][k] = make_float4(pi[4 * k], pi[4 * k + 1], pi[4 * k + 2], pi[4 * k + 3]);
    }
    wrt[g] = pr[24];
    wit[g] = pi[24];
    bias[g] = biasAll[dir * 400 + g * 100 + u];
  }
  const int qq_u = u / 25, pp_u = u - (u / 25) * 25;
  int xq0 = 0, xp0 = 0;
  if (tid < 100) { xq0 = tid / 25; xp0 = tid - (tid / 25) * 25; }

  // ---- prologue: xe[s0] -> xe_q[0]; h_q[0] = 0
  if (tid < 100) xe_q[0][xq0][xp0] = emb[(size_t)xb[s0] * 100 + tid];
  if (tid < 112) ((float*)h_q[0])[tid] = 0.f;
  __syncthreads();

  // gemv0: p = Wih @ xe[s0]  (consumed by step 0's activation)
  float p[4];
  {
    const float* xq = &xe_q[0][q][0];
    float xt = xq[24];
    float e0 = wit[0] * xt, e1 = wit[1] * xt, e2 = wit[2] * xt, e3 = wit[3] * xt;
#pragma unroll
    for (int k = 0; k < 6; ++k) {
      float4 xv = *(const float4*)(xq + 4 * k);
      e0 += wi4[0][k].x * xv.x + wi4[0][k].y * xv.y + wi4[0][k].z * xv.z + wi4[0][k].w * xv.w;
      e1 += wi4[1][k].x * xv.x + wi4[1][k].y * xv.y + wi4[1][k].z * xv.z + wi4[1][k].w * xv.w;
      e2 += wi4[2][k].x * xv.x + wi4[2][k].y * xv.y + wi4[2][k].z * xv.z + wi4[2][k].w * xv.w;
      e3 += wi4[3][k].x * xv.x + wi4[3][k].y * xv.y + wi4[3][k].z * xv.z + wi4[3][k].w * xv.w;
    }
    p[0] = qred(e0); p[1] = qred(e1); p[2] = qred(e2); p[3] = qred(e3);
  }

  // stage xe[s0+sstep] -> xe_q[1]; prime the x-index pipeline (2 ahead)
  if (tid < 100) xe_q[1][xq0][xp0] = emb[(size_t)xb[s0 + sstep] * 100 + tid];
  int xidx = xb[min(511, max(0, s0 + 2 * sstep))];
  __syncthreads();

  float c = 0.f;
  for (int t = 0; t < 512; ++t) {
    int s = s0 + sstep * t;
    // prefetch emb row for step t+2 (staged at step end), x-index for t+3
    float v = 0.f;
    if (tid < 100) v = emb[(size_t)xidx * 100 + tid];
    xidx = xb[min(511, max(0, s + 3 * sstep))];

    const float* hq = &h_q[t & 1][q][0];
    const float* xq = &xe_q[(t + 1) & 1][q][0];
    float ht = hq[24], xt = xq[24];
    float r0 = wrt[0] * ht, r1 = wrt[1] * ht, r2 = wrt[2] * ht, r3 = wrt[3] * ht;
    float e0 = wit[0] * xt, e1 = wit[1] * xt, e2 = wit[2] * xt, e3 = wit[3] * xt;
#pragma unroll
    for (int k = 0; k < 6; ++k) {
      float4 hv = *(const float4*)(hq + 4 * k);
      float4 xv = *(const float4*)(xq + 4 * k);
      r0 += wr4[0][k].x * hv.x + wr4[0][k].y * hv.y + wr4[0][k].z * hv.z + wr4[0][k].w * hv.w;
      r1 += wr4[1][k].x * hv.x + wr4[1][k].y * hv.y + wr4[1][k].z * hv.z + wr4[1][k].w * hv.w;
      r2 += wr4[2][k].x * hv.x + wr4[2][k].y * hv.y + wr4[2][k].z * hv.z + wr4[2][k].w * hv.w;
      r3 += wr4[3][k].x * hv.x + wr4[3][k].y * hv.y + wr4[3][k].z * hv.z + wr4[3][k].w * hv.w;
      e0 += wi4[0][k].x * xv.x + wi4[0][k].y * xv.y + wi4[0][k].z * xv.z + wi4[0][k].w * xv.w;
      e1 += wi4[1][k].x * xv.x + wi4[1][k].y * xv.y + wi4[1][k].z * xv.z + wi4[1][k].w * xv.w;
      e2 += wi4[2][k].x * xv.x + wi4[2][k].y * xv.y + wi4[2][k].z * xv.z + wi4[2][k].w * xv.w;
      e3 += wi4[3][k].x * xv.x + wi4[3][k].y * xv.y + wi4[3][k].z * xv.z + wi4[3][k].w * xv.w;
    }
    r0 = qred(r0); r1 = qred(r1); r2 = qred(r2); r3 = qred(r3);
    e0 = qred(e0); e1 = qred(e1); e2 = qred(e2); e3 = qred(e3);

    if (q == 0) {
      float gi = r0 + p[0] + bias[0];
      float gf = r1 + p[1] + bias[1];
      float gg = r2 + p[2] + bias[2];
      float go = r3 + p[3] + bias[3];
      c = sigf(gf) * c + sigf(gi) * tanhf_(gg);
      float h = sigf(go) * tanhf_(c);
      h_q[(t + 1) & 1][qq_u][pp_u] = h;
      hout[(size_t)s * 100 + u] = h;
    }
    p[0] = e0; p[1] = e1; p[2] = e2; p[3] = e3;
    if (tid < 100) xe_q[t & 1][xq0][xp0] = v;  // xe row s+2*sstep, read at t+2
    __syncthreads();
  }
}

// ---------------------------------------------------------------- emis ----
// em[row][v] = sum_d hcat[row][d] * M2[v][d] + c0[v]; 32 rows/block
__global__ __launch_bounds__(128) void emis_kernel(
    const float* __restrict__ hfB, const float* __restrict__ hbB,
    const float* __restrict__ M2g, const float* __restrict__ c0g,
    float* __restrict__ em) {
  __shared__ __align__(16) float hrow[32 * 204];
  __shared__ __align__(16) float M2l[4000];
  __shared__ float c0l[20];
  int tid = threadIdx.x;
  int row0 = blockIdx.x * 32;
  for (int i = tid; i < 800; i += 128) {
    int r = i / 25, q = i - r * 25;
    *(float4*)&hrow[r * 204 + q * 4] =
        *(const float4*)(hfB + (size_t)(row0 + r) * 100 + q * 4);
    *(float4*)&hrow[r * 204 + 100 + q * 4] =
        *(const float4*)(hbB + (size_t)(row0 + r) * 100 + q * 4);
  }
  for (int i = tid; i < 1000; i += 128) ((float4*)M2l)[i] = ((const float4*)M2g)[i];
  if (tid < 20) c0l[tid] = (tid < 19) ? c0g[tid] : 0.f;
  __syncthreads();

  int r = tid >> 2, q = tid & 3;
  int v0 = q * 5;
  float acc[5] = {0.f, 0.f, 0.f, 0.f, 0.f};
  for (int k = 0; k < 200; k += 4) {
    float4 h4 = *(const float4*)&hrow[r * 204 + k];
#pragma unroll
    for (int i = 0; i < 5; ++i) {
      float4 m4 = *(const float4*)&M2l[(v0 + i) * 200 + k];
      acc[i] += h4.x * m4.x + h4.y * m4.y + h4.z * m4.z + h4.w * m4.w;
    }
  }
  int nv = (q == 3) ? 4 : 5;
  for (int i = 0; i < nv; ++i)
    em[(size_t)(row0 + r) * 19 + v0 + i] = acc[i] + c0l[v0 + i];
}

// ----------------------------------------------------------------- crf ----
// one wave per batch element; log2 domain (native v_exp/v_log). BOS col and
// EOS row are annihilated by the -10000 mask (exp underflows to 0 in fp32
// exactly as in the reference), so the live recursion is 17x17. Alphas are
// broadcast lane0..16 -> all lanes via __shfl (no LDS, no per-step barrier).
__global__ __launch_bounds__(64) void crf_kernel(
    const float* __restrict__ em, const int* __restrict__ target,
    const float* __restrict__ T, float* __restrict__ res) {
  __shared__ float em_l[512 * 19];
  __shared__ float T_l[361];
  __shared__ int tgt_l[512];
  constexpr float LOG2E = 1.4426950408889634f;
  constexpr float LN2 = 0.6931471805599453f;
  int b = blockIdx.x, lane = threadIdx.x;
  const float* emsrc = em + (size_t)b * 512 * 19;
  for (int i = lane; i < 512 * 19; i += 64) em_l[i] = emsrc[i] * LOG2E;
  for (int i = lane; i < 361; i += 64) T_l[i] = T[i] * LOG2E;
  for (int i = lane; i < 512; i += 64) tgt_l[i] = target[b * 512 + i];
  __syncthreads();

  float sc = 0.f;
  for (int t = lane; t < 512; t += 64) {
    int tg = tgt_l[t];
    sc += em_l[t * 19 + tg];
    if (t < 511) sc += T_l[tg * 19 + tgt_l[t + 1]];
  }
#pragma unroll
  for (int off = 32; off >= 1; off >>= 1) sc += __shfl_xor(sc, off);

  int v = (lane < 17) ? lane : 0;
  float Tcol[17];
#pragma unroll
  for (int u = 0; u < 17; ++u) Tcol[u] = T_l[u * 19 + v];
  float a[17];
#pragma unroll
  for (int u = 0; u < 17; ++u) a[u] = T_l[BOS_ * 19 + u] + em_l[u];

  for (int t = 1; t < 512; ++t) {
    float xx[17];
#pragma unroll
    for (int u = 0; u < 17; ++u) xx[u] = a[u] + Tcol[u];
    float m = xx[0];
#pragma unroll
    for (int u = 1; u < 17; ++u) m = fmaxf(m, xx[u]);
    float s0 = 0.f, s1 = 0.f, s2 = 0.f, s3 = 0.f;
#pragma unroll
    for (int u = 0; u < 16; u += 4) {
      s0 += exp2f(xx[u] - m);
      s1 += exp2f(xx[u + 1] - m);
      s2 += exp2f(xx[u + 2] - m);
      s3 += exp2f(xx[u + 3] - m);
    }
    s0 += exp2f(xx[16] - m);
    float na = m + log2f((s0 + s1) + (s2 + s3)) + em_l[t * 19 + v];
#pragma unroll
    for (int u = 0; u < 17; ++u) a[u] = __shfl(na, u, 64);
  }

  float xx[17];
#pragma unroll
  for (int u = 0; u < 17; ++u) xx[u] = a[u] + T_l[u * 19 + EOS_];
  float m = xx[0];
#pragma unroll
  for (int u = 1; u < 17; ++u) m = fmaxf(m, xx[u]);
  float ssum = 0.f;
#pragma unroll
  for (int u = 0; u < 17; ++u) ssum += exp2f(xx[u] - m);
  float part = m + log2f(ssum);

  if (lane == 0) {
    float score = sc + T_l[BOS_ * 19 + tgt_l[0]] + T_l[tgt_l[511] * 19 + EOS_];
    res[b] = (score - part) * LN2;
  }
}

// ------------------------------------------------------------- final -----
__global__ void final_kernel(const float* __restrict__ res, float* __restrict__ out) {
  int lane = threadIdx.x;
  float s = 0.f;
  for (int i = lane; i < 256; i += 64) s += res[i];
#pragma unroll
  for (int off = 32; off >= 1; off >>= 1) s += __shfl_xor(s, off);
  if (lane == 0) out[0] = -s * (1.0f / 256.0f);
}

// ---------------------------------------------------------------------------
extern "C" void kernel_launch(void* const* d_in, const int* in_sizes, int n_in,
                              void* d_out, int out_size, void* d_ws, size_t ws_size,
                              hipStream_t stream) {
  const int*   x      = (const int*)d_in[0];
  const int*   target = (const int*)d_in[1];
  const float* emb    = (const float*)d_in[2];
  const float* Wih_f  = (const float*)d_in[3];
  const float* Whh_f  = (const float*)d_in[4];
  const float* bih_f  = (const float*)d_in[5];
  const float* bhh_f  = (const float*)d_in[6];
  const float* Wih_b  = (const float*)d_in[7];
  const float* Whh_b  = (const float*)d_in[8];
  const float* bih_b  = (const float*)d_in[9];
  const float* bhh_b  = (const float*)d_in[10];
  const float* W1     = (const float*)d_in[11];
  const float* b1     = (const float*)d_in[12];
  const float* W2     = (const float*)d_in[13];
  const float* b2     = (const float*)d_in[14];
  const float* trans  = (const float*)d_in[15];
  float* out = (float*)d_out;

  float* ws = (float*)d_ws;
  float* em      = ws;                          // BS*19
  float* M2      = em + (size_t)BS_ * 19;       // 4000
  float* c0      = M2 + 4000;                   // 64
  float* biasAll = c0 + 64;                     // 1024
  float* res     = biasAll + 1024;              // 256
  float* hfbuf   = res + 256;                   // BS*100
  float* hbbuf   = hfbuf + (size_t)BS_ * 100;   // BS*100  (total ~115 MB)

  prep_kernel<<<1, 256, 0, stream>>>(W1, b1, W2, b2, bih_f, bhh_f, bih_b, bhh_b,
                                     M2, c0, biasAll);
  scan_fused_kernel<<<512, 400, 0, stream>>>(x, emb, Wih_f, Wih_b, Whh_f, Whh_b,
                                             biasAll, hfbuf, hbbuf);
  emis_kernel<<<BS_ / 32, 128, 0, stream>>>(hfbuf, hbbuf, M2, c0, em);
  crf_kernel<<<B_, 64, 0, stream>>>(em, target, trans, res);
  final_kernel<<<1, 64, 0, stream>>>(res, out);
}

// Round 8
// 1353.838 us; speedup vs baseline: 3.6453x; 1.4936x over previous
//
#include <hip/hip_runtime.h>
#include <hip/hip_bf16.h>

#define DI __device__ __forceinline__

constexpr int B_ = 256, S_ = 512, I_ = 100, NB_ = 19, H4_ = 400;
constexpr int BOS_ = 17, EOS_ = 18;
constexpr int BS_ = B_ * S_;
constexpr int V_ = 30000;

typedef float v2f __attribute__((ext_vector_type(2)));
typedef float v4f __attribute__((ext_vector_type(4)));

DI float sigf(float x) { return 1.0f / (1.0f + __expf(-x)); }
DI float tanhf_(float x) {
  float e = __expf(-2.0f * fabsf(x));
  float r = (1.0f - e) / (1.0f + e);
  return copysignf(r, x);
}

// quad (4-lane) sum via DPP quad_perm: lanes 4k..4k+3 all end with the sum
DI float qred(float a) {
  a += __int_as_float(__builtin_amdgcn_mov_dpp(__float_as_int(a), 0xB1, 0xF, 0xF, true));
  a += __int_as_float(__builtin_amdgcn_mov_dpp(__float_as_int(a), 0x4E, 0xF, 0xF, true));
  return a;
}

// ---------------------------------------------------------------- prep ----
// M2[19][200] = W2 @ W1 ; c0[19] = W2@b1 + b2 ; biasAll[800] = bih+bhh (f|b)
__global__ __launch_bounds__(256) void prep_kernel(
    const float* __restrict__ W1, const float* __restrict__ b1,
    const float* __restrict__ W2, const float* __restrict__ b2,
    const float* __restrict__ bih_f, const float* __restrict__ bhh_f,
    const float* __restrict__ bih_b, const float* __restrict__ bhh_b,
    float* __restrict__ M2, float* __restrict__ c0, float* __restrict__ biasAll) {
  int t = threadIdx.x;
  for (int c = t; c < 800; c += 256)
    biasAll[c] = (c < 400) ? (bih_f[c] + bhh_f[c]) : (bih_b[c - 400] + bhh_b[c - 400]);
  if (t < 19) {
    float acc = b2[t];
    for (int j = 0; j < 100; ++j) acc += W2[t * 100 + j] * b1[j];
    c0[t] = acc;
  }
  for (int i = t; i < 19 * 200; i += 256) {
    int v = i / 200, d = i - v * 200;
    float acc = 0.f;
    for (int j = 0; j < 100; ++j) acc += W2[v * 100 + j] * W1[j * 200 + d];
    M2[i] = acc;
  }
  for (int i = 3800 + t; i < 4000; i += 256) M2[i] = 0.f;  // pad for float4 loads
}

// ------------------------------------------------------------- ewbuild ----
// EW[v][c] = emb[v] . Wih[c] + bias[c], c in [0,800): f gates | b gates.
// Same 64x80 tile / 4x5 micro as the old pregemm, A = emb rows directly.
__global__ __launch_bounds__(256) void ewbuild_kernel(
    const float* __restrict__ emb, const float* __restrict__ Wih_f,
    const float* __restrict__ Wih_b, const float* __restrict__ biasAll,
    float* __restrict__ EW) {
  __shared__ __align__(16) float Al[64 * 100];
  __shared__ __align__(16) float Bl[80 * 100];
  int tid = threadIdx.x;
  int ct = blockIdx.x;  // 0..9
  int rt = blockIdx.y;  // 0..468
  int row0 = rt * 64;
  const float* Wsrc = (ct < 5) ? (Wih_f + (size_t)ct * 8000)
                               : (Wih_b + (size_t)(ct - 5) * 8000);
  const float4* bsrc = (const float4*)Wsrc;
  float4* bdst = (float4*)Bl;
  for (int i = tid; i < 2000; i += 256) bdst[i] = bsrc[i];
  float4* adst = (float4*)Al;
  for (int i = tid; i < 1600; i += 256) {
    int r = i / 25, qq = i - r * 25;
    int v = min(row0 + r, V_ - 1);
    adst[i] = ((const float4*)(emb + (size_t)v * 100))[qq];
  }
  __syncthreads();

  int tr = tid >> 4, tc = tid & 15;
  int r0 = tr * 4, c0l = tc * 5;
  float acc[4][5];
#pragma unroll
  for (int i = 0; i < 4; ++i)
#pragma unroll
    for (int j = 0; j < 5; ++j) acc[i][j] = 0.f;

  for (int k = 0; k < 100; k += 4) {
    float4 a[4], b[5];
#pragma unroll
    for (int i = 0; i < 4; ++i) a[i] = *(const float4*)&Al[(r0 + i) * 100 + k];
#pragma unroll
    for (int j = 0; j < 5; ++j) b[j] = *(const float4*)&Bl[(c0l + j) * 100 + k];
#pragma unroll
    for (int i = 0; i < 4; ++i)
#pragma unroll
      for (int j = 0; j < 5; ++j) {
        acc[i][j] += a[i].x * b[j].x;
        acc[i][j] += a[i].y * b[j].y;
        acc[i][j] += a[i].z * b[j].z;
        acc[i][j] += a[i].w * b[j].w;
      }
  }

  int colb = (ct < 5) ? (ct * 80 + c0l) : (400 + (ct - 5) * 80 + c0l);
#pragma unroll
  for (int i = 0; i < 4; ++i) {
    int vr = row0 + r0 + i;
    if (vr < V_) {
#pragma unroll
      for (int j = 0; j < 5; ++j)
        EW[(size_t)vr * 800 + colb + j] = acc[i][j] + biasAll[ct * 80 + c0l + j];
    }
  }
}

// ---------------------------------------------------------------- scan ----
// LSTM scan, input contribution gathered from EW (no input GEMV, no xe).
// One block (400 thr) per (seq-PAIR, dir): 256 blocks = 1/CU, ONE round.
// Thread (u,q) holds quarter q of Whh gate rows {u,100+u,200+u,300+u} as
// 13 packed v2f (zero-padded tail) -> v_pk_fma_f32, and computes BOTH
// sequences' quarter dots each step. DPP quad-reduce; lane q==0 activates
// seq A, q==1 seq B. h_q reads are same-address broadcasts (conflict-free).
__global__ __launch_bounds__(400, 1) void scan_fused2_kernel(
    const int* __restrict__ x, const float* __restrict__ EW,
    const float* __restrict__ Whh_f, const float* __restrict__ Whh_b,
    float* __restrict__ hf, float* __restrict__ hb) {
  __shared__ __align__(16) float h_q[2][2][4][28];  // [buf][seq][quarter][25+pad]
  int bid = blockIdx.x;
  int pair = bid >> 1, dir = bid & 1;
  int tid = threadIdx.x;
  int u = tid >> 2, q = tid & 3;
  const float* Whh = dir ? Whh_b : Whh_f;
  float* hdir = dir ? hb : hf;
  float* houtA = hdir + (size_t)(pair * 2) * 51200;
  float* houtB = hdir + (size_t)(pair * 2 + 1) * 51200;
  const int* xbA = x + (size_t)(pair * 2) * 512;
  const int* xbB = x + (size_t)(pair * 2 + 1) * 512;
  const int dirb = dir * 400;
  const int s0 = dir ? 511 : 0, sstep = dir ? -1 : 1;

  // Whh quarter fragments, packed: 13 v2f per gate row (tail {w24, 0})
  v2f w2[4][13];
#pragma unroll
  for (int g = 0; g < 4; ++g) {
    const float* pr = Whh + (size_t)(g * 100 + u) * 100 + q * 25;
#pragma unroll
    for (int k = 0; k < 12; ++k) w2[g][k] = v2f{pr[2 * k], pr[2 * k + 1]};
    w2[g][12] = v2f{pr[24], 0.f};
  }
  const int uq = u / 25, up = u - uq * 25;
  float* houtme = (q & 1) ? houtB : houtA;

  for (int i = tid; i < 448; i += 400) ((float*)h_q)[i] = 0.f;  // incl. pads

  // p pipeline: pc = input+bias contribution for step t (from EW)
  float pc[4] = {0.f, 0.f, 0.f, 0.f}, pn[4];
  int xnA = xbA[s0 + sstep], xnB = xbB[s0 + sstep];
  {
    int xcA = xbA[s0], xcB = xbB[s0];
    if (q < 2) {
      const float* ewr = EW + (size_t)(q ? xcB : xcA) * 800 + dirb + u;
#pragma unroll
      for (int g = 0; g < 4; ++g) pc[g] = ewr[g * 100];
    }
  }
  float c = 0.f;
  __syncthreads();

  for (int t = 0; t < 512; ++t) {
    int s = s0 + sstep * t;
    // issue EW loads for step t+1 (latency hidden under this step's dots)
    pn[0] = pn[1] = pn[2] = pn[3] = 0.f;
    if (q < 2) {
      const float* ewr = EW + (size_t)(q ? xnB : xnA) * 800 + dirb + u;
#pragma unroll
      for (int g = 0; g < 4; ++g) pn[g] = ewr[g * 100];
    }
    int s2 = min(511, max(0, s + 2 * sstep));
    xnA = xbA[s2]; xnB = xbB[s2];

    int cb = t & 1, nb = cb ^ 1;
    const float* hA = &h_q[cb][0][q][0];
    const float* hB = &h_q[cb][1][q][0];
    v2f ra[4], rb[4];
#pragma unroll
    for (int g = 0; g < 4; ++g) { ra[g] = v2f{0.f, 0.f}; rb[g] = v2f{0.f, 0.f}; }
#pragma unroll
    for (int m = 0; m < 6; ++m) {
      v4f a4 = *(const v4f*)(hA + 4 * m);
      v4f b4 = *(const v4f*)(hB + 4 * m);
      v2f alo = v2f{a4.x, a4.y}, ahi = v2f{a4.z, a4.w};
      v2f blo = v2f{b4.x, b4.y}, bhi = v2f{b4.z, b4.w};
#pragma unroll
      for (int g = 0; g < 4; ++g) {
        ra[g] += w2[g][2 * m] * alo;
        ra[g] += w2[g][2 * m + 1] * ahi;
        rb[g] += w2[g][2 * m] * blo;
        rb[g] += w2[g][2 * m + 1] * bhi;
      }
    }
    {
      v2f at = *(const v2f*)(hA + 24);  // element 25 is the zeroed pad
      v2f bt = *(const v2f*)(hB + 24);
#pragma unroll
      for (int g = 0; g < 4; ++g) { ra[g] += w2[g][12] * at; rb[g] += w2[g][12] * bt; }
    }

    float gate[4];
#pragma unroll
    for (int g = 0; g < 4; ++g) {
      float sa = qred(ra[g].x + ra[g].y);
      float sb = qred(rb[g].x + rb[g].y);
      gate[g] = ((q & 1) ? sb : sa) + pc[g];
    }
    c = sigf(gate[1]) * c + sigf(gate[0]) * tanhf_(gate[2]);
    float h = sigf(gate[3]) * tanhf_(c);
    if (q < 2) {
      h_q[nb][q][uq][up] = h;
      houtme[(size_t)s * 100 + u] = h;
    }
    pc[0] = pn[0]; pc[1] = pn[1]; pc[2] = pn[2]; pc[3] = pn[3];
    __syncthreads();
  }
}

// ---------------------------------------------------------------- emis ----
// em[row][v] = sum_d hcat[row][d] * M2[v][d] + c0[v]; 32 rows/block
__global__ __launch_bounds__(128) void emis_kernel(
    const float* __restrict__ hfB, const float* __restrict__ hbB,
    const float* __restrict__ M2g, const float* __restrict__ c0g,
    float* __restrict__ em) {
  __shared__ __align__(16) float hrow[32 * 204];
  __shared__ __align__(16) float M2l[4000];
  __shared__ float c0l[20];
  int tid = threadIdx.x;
  int row0 = blockIdx.x * 32;
  for (int i = tid; i < 800; i += 128) {
    int r = i / 25, q = i - r * 25;
    *(float4*)&hrow[r * 204 + q * 4] =
        *(const float4*)(hfB + (size_t)(row0 + r) * 100 + q * 4);
    *(float4*)&hrow[r * 204 + 100 + q * 4] =
        *(const float4*)(hbB + (size_t)(row0 + r) * 100 + q * 4);
  }
  for (int i = tid; i < 1000; i += 128) ((float4*)M2l)[i] = ((const float4*)M2g)[i];
  if (tid < 20) c0l[tid] = (tid < 19) ? c0g[tid] : 0.f;
  __syncthreads();

  int r = tid >> 2, q = tid & 3;
  int v0 = q * 5;
  float acc[5] = {0.f, 0.f, 0.f, 0.f, 0.f};
  for (int k = 0; k < 200; k += 4) {
    float4 h4 = *(const float4*)&hrow[r * 204 + k];
#pragma unroll
    for (int i = 0; i < 5; ++i) {
      float4 m4 = *(const float4*)&M2l[(v0 + i) * 200 + k];
      acc[i] += h4.x * m4.x + h4.y * m4.y + h4.z * m4.z + h4.w * m4.w;
    }
  }
  int nv = (q == 3) ? 4 : 5;
  for (int i = 0; i < nv; ++i)
    em[(size_t)(row0 + r) * 19 + v0 + i] = acc[i] + c0l[v0 + i];
}

// ----------------------------------------------------------------- crf ----
// one wave per batch element; log2 domain (native v_exp/v_log). BOS col and
// EOS row are annihilated by the -10000 mask (exp underflows to 0 in fp32
// exactly as in the reference), so the live recursion is 17x17. Alphas are
// broadcast lane0..16 -> all lanes via __shfl (no LDS, no per-step barrier).
__global__ __launch_bounds__(64) void crf_kernel(
    const float* __restrict__ em, const int* __restrict__ target,
    const float* __restrict__ T, float* __restrict__ res) {
  __shared__ float em_l[512 * 19];
  __shared__ float T_l[361];
  __shared__ int tgt_l[512];
  constexpr float LOG2E = 1.4426950408889634f;
  constexpr float LN2 = 0.6931471805599453f;
  int b = blockIdx.x, lane = threadIdx.x;
  const float* emsrc = em + (size_t)b * 512 * 19;
  for (int i = lane; i < 512 * 19; i += 64) em_l[i] = emsrc[i] * LOG2E;
  for (int i = lane; i < 361; i += 64) T_l[i] = T[i] * LOG2E;
  for (int i = lane; i < 512; i += 64) tgt_l[i] = target[b * 512 + i];
  __syncthreads();

  float sc = 0.f;
  for (int t = lane; t < 512; t += 64) {
    int tg = tgt_l[t];
    sc += em_l[t * 19 + tg];
    if (t < 511) sc += T_l[tg * 19 + tgt_l[t + 1]];
  }
#pragma unroll
  for (int off = 32; off >= 1; off >>= 1) sc += __shfl_xor(sc, off);

  int v = (lane < 17) ? lane : 0;
  float Tcol[17];
#pragma unroll
  for (int u = 0; u < 17; ++u) Tcol[u] = T_l[u * 19 + v];
  float a[17];
#pragma unroll
  for (int u = 0; u < 17; ++u) a[u] = T_l[BOS_ * 19 + u] + em_l[u];

  for (int t = 1; t < 512; ++t) {
    float xx[17];
#pragma unroll
    for (int u = 0; u < 17; ++u) xx[u] = a[u] + Tcol[u];
    float m = xx[0];
#pragma unroll
    for (int u = 1; u < 17; ++u) m = fmaxf(m, xx[u]);
    float s0 = 0.f, s1 = 0.f, s2 = 0.f, s3 = 0.f;
#pragma unroll
    for (int u = 0; u < 16; u += 4) {
      s0 += exp2f(xx[u] - m);
      s1 += exp2f(xx[u + 1] - m);
      s2 += exp2f(xx[u + 2] - m);
      s3 += exp2f(xx[u + 3] - m);
    }
    s0 += exp2f(xx[16] - m);
    float na = m + log2f((s0 + s1) + (s2 + s3)) + em_l[t * 19 + v];
#pragma unroll
    for (int u = 0; u < 17; ++u) a[u] = __shfl(na, u, 64);
  }

  float xx[17];
#pragma unroll
  for (int u = 0; u < 17; ++u) xx[u] = a[u] + T_l[u * 19 + EOS_];
  float m = xx[0];
#pragma unroll
  for (int u = 1; u < 17; ++u) m = fmaxf(m, xx[u]);
  float ssum = 0.f;
#pragma unroll
  for (int u = 0; u < 17; ++u) ssum += exp2f(xx[u] - m);
  float part = m + log2f(ssum);

  if (lane == 0) {
    float score = sc + T_l[BOS_ * 19 + tgt_l[0]] + T_l[tgt_l[511] * 19 + EOS_];
    res[b] = (score - part) * LN2;
  }
}

// ------------------------------------------------------------- final -----
__global__ void final_kernel(const float* __restrict__ res, float* __restrict__ out) {
  int lane = threadIdx.x;
  float s = 0.f;
  for (int i = lane; i < 256; i += 64) s += res[i];
#pragma unroll
  for (int off = 32; off >= 1; off >>= 1) s += __shfl_xor(s, off);
  if (lane == 0) out[0] = -s * (1.0f / 256.0f);
}

// ---------------------------------------------------------------------------
extern "C" void kernel_launch(void* const* d_in, const int* in_sizes, int n_in,
                              void* d_out, int out_size, void* d_ws, size_t ws_size,
                              hipStream_t stream) {
  const int*   x      = (const int*)d_in[0];
  const int*   target = (const int*)d_in[1];
  const float* emb    = (const float*)d_in[2];
  const float* Wih_f  = (const float*)d_in[3];
  const float* Whh_f  = (const float*)d_in[4];
  const float* bih_f  = (const float*)d_in[5];
  const float* bhh_f  = (const float*)d_in[6];
  const float* Wih_b  = (const float*)d_in[7];
  const float* Whh_b  = (const float*)d_in[8];
  const float* bih_b  = (const float*)d_in[9];
  const float* bhh_b  = (const float*)d_in[10];
  const float* W1     = (const float*)d_in[11];
  const float* b1     = (const float*)d_in[12];
  const float* W2     = (const float*)d_in[13];
  const float* b2     = (const float*)d_in[14];
  const float* trans  = (const float*)d_in[15];
  float* out = (float*)d_out;

  float* ws = (float*)d_ws;
  float* em      = ws;                          // BS*19          (~10 MB)
  float* M2      = em + (size_t)BS_ * 19;       // 4000
  float* c0      = M2 + 4000;                   // 64
  float* biasAll = c0 + 64;                     // 1024
  float* res     = biasAll + 1024;              // 256
  float* hfbuf   = res + 256;                   // BS*100         (~52 MB)
  float* hbbuf   = hfbuf + (size_t)BS_ * 100;   // BS*100         (~52 MB)
  float* EW      = hbbuf + (size_t)BS_ * 100;   // V*800          (~96 MB)

  prep_kernel<<<1, 256, 0, stream>>>(W1, b1, W2, b2, bih_f, bhh_f, bih_b, bhh_b,
                                     M2, c0, biasAll);
  ewbuild_kernel<<<dim3(10, (V_ + 63) / 64), 256, 0, stream>>>(emb, Wih_f, Wih_b,
                                                               biasAll, EW);
  scan_fused2_kernel<<<256, 400, 0, stream>>>(x, EW, Whh_f, Whh_b, hfbuf, hbbuf);
  emis_kernel<<<BS_ / 32, 128, 0, stream>>>(hfbuf, hbbuf, M2, c0, em);
  crf_kernel<<<B_, 64, 0, stream>>>(em, target, trans, res);
  final_kernel<<<1, 64, 0, stream>>>(res, out);
}

// Round 9
// 1229.946 us; speedup vs baseline: 4.0125x; 1.1007x over previous
//
#include <hip/hip_runtime.h>
#include <hip/hip_bf16.h>

#define DI __device__ __forceinline__

constexpr int B_ = 256, S_ = 512, I_ = 100, NB_ = 19, H4_ = 400;
constexpr int BOS_ = 17, EOS_ = 18;
constexpr int BS_ = B_ * S_;
constexpr int V_ = 30000;

typedef float v2f __attribute__((ext_vector_type(2)));
typedef float v4f __attribute__((ext_vector_type(4)));

DI float sigf(float x) { return 1.0f / (1.0f + __expf(-x)); }
DI float tanhf_(float x) {
  float e = __expf(-2.0f * fabsf(x));
  float r = (1.0f - e) / (1.0f + e);
  return copysignf(r, x);
}

// quad (4-lane) sum via DPP quad_perm: lanes 4k..4k+3 all end with the sum
DI float qred(float a) {
  a += __int_as_float(__builtin_amdgcn_mov_dpp(__float_as_int(a), 0xB1, 0xF, 0xF, true));
  a += __int_as_float(__builtin_amdgcn_mov_dpp(__float_as_int(a), 0x4E, 0xF, 0xF, true));
  return a;
}

// ---------------------------------------------------------------- prep ----
// M2[19][200] = W2 @ W1 ; c0[19] = W2@b1 + b2 ; biasAll[800] = bih+bhh (f|b)
__global__ __launch_bounds__(256) void prep_kernel(
    const float* __restrict__ W1, const float* __restrict__ b1,
    const float* __restrict__ W2, const float* __restrict__ b2,
    const float* __restrict__ bih_f, const float* __restrict__ bhh_f,
    const float* __restrict__ bih_b, const float* __restrict__ bhh_b,
    float* __restrict__ M2, float* __restrict__ c0, float* __restrict__ biasAll) {
  int t = threadIdx.x;
  for (int c = t; c < 800; c += 256)
    biasAll[c] = (c < 400) ? (bih_f[c] + bhh_f[c]) : (bih_b[c - 400] + bhh_b[c - 400]);
  if (t < 19) {
    float acc = b2[t];
    for (int j = 0; j < 100; ++j) acc += W2[t * 100 + j] * b1[j];
    c0[t] = acc;
  }
  for (int i = t; i < 19 * 200; i += 256) {
    int v = i / 200, d = i - v * 200;
    float acc = 0.f;
    for (int j = 0; j < 100; ++j) acc += W2[v * 100 + j] * W1[j * 200 + d];
    M2[i] = acc;
  }
  for (int i = 3800 + t; i < 4000; i += 256) M2[i] = 0.f;  // pad for float4 loads
}

// ------------------------------------------------------------- ewbuild ----
// EW[v][c] = emb[v] . Wih[c] + bias[c], c in [0,800): f gates | b gates.
// 64x80 tile, 256 thr. STRIDED micro-tile (rows tr+16i, cols tc+16j):
// LDS A-read bank = (4*tr + k) % 32 -> 2-way (free); consecutive-row micro
// was 8-way on banks {0,16}.
__global__ __launch_bounds__(256) void ewbuild_kernel(
    const float* __restrict__ emb, const float* __restrict__ Wih_f,
    const float* __restrict__ Wih_b, const float* __restrict__ biasAll,
    float* __restrict__ EW) {
  __shared__ __align__(16) float Al[64 * 100];
  __shared__ __align__(16) float Bl[80 * 100];
  int tid = threadIdx.x;
  int ct = blockIdx.x;  // 0..9
  int rt = blockIdx.y;  // 0..468
  int row0 = rt * 64;
  const float* Wsrc = (ct < 5) ? (Wih_f + (size_t)ct * 8000)
                               : (Wih_b + (size_t)(ct - 5) * 8000);
  const float4* bsrc = (const float4*)Wsrc;
  float4* bdst = (float4*)Bl;
  for (int i = tid; i < 2000; i += 256) bdst[i] = bsrc[i];
  float4* adst = (float4*)Al;
  for (int i = tid; i < 1600; i += 256) {
    int r = i / 25, qq = i - r * 25;
    int v = min(row0 + r, V_ - 1);
    adst[i] = ((const float4*)(emb + (size_t)v * 100))[qq];
  }
  __syncthreads();

  int tr = tid >> 4, tc = tid & 15;
  float acc[4][5];
#pragma unroll
  for (int i = 0; i < 4; ++i)
#pragma unroll
    for (int j = 0; j < 5; ++j) acc[i][j] = 0.f;

  for (int k = 0; k < 100; k += 4) {
    float4 a[4], b[5];
#pragma unroll
    for (int i = 0; i < 4; ++i) a[i] = *(const float4*)&Al[(tr + 16 * i) * 100 + k];
#pragma unroll
    for (int j = 0; j < 5; ++j) b[j] = *(const float4*)&Bl[(tc + 16 * j) * 100 + k];
#pragma unroll
    for (int i = 0; i < 4; ++i)
#pragma unroll
      for (int j = 0; j < 5; ++j) {
        acc[i][j] += a[i].x * b[j].x;
        acc[i][j] += a[i].y * b[j].y;
        acc[i][j] += a[i].z * b[j].z;
        acc[i][j] += a[i].w * b[j].w;
      }
  }

  int base = (ct < 5) ? (ct * 80) : (400 + (ct - 5) * 80);
#pragma unroll
  for (int i = 0; i < 4; ++i) {
    int vr = row0 + tr + 16 * i;
    if (vr < V_) {
#pragma unroll
      for (int j = 0; j < 5; ++j) {
        int cc = tc + 16 * j;
        EW[(size_t)vr * 800 + base + cc] = acc[i][j] + biasAll[ct * 80 + cc];
      }
    }
  }
}

// ---------------------------------------------------------------- scan ----
// LSTM scan; input+bias contribution gathered from EW (1 scalar/thread/seq,
// folded pre-qred on the matching gate lane). One block (400 thr) per
// (seq-PAIR, dir): 256 blocks = 1/CU. Thread (u,q) holds quarter q of Whh
// gate rows {u,100+u,200+u,300+u} (104 VGPRs). x-indices preloaded to LDS
// in scan order; EW prefetch 2 steps deep via unroll-2 (named reg pairs).
// launch_bounds(400,2): 256-VGPR cap -> weights stay in arch VGPRs.
__global__ __launch_bounds__(400, 2) void scan_fused3_kernel(
    const int* __restrict__ x, const float* __restrict__ EW,
    const float* __restrict__ Whh_f, const float* __restrict__ Whh_b,
    float* __restrict__ hf, float* __restrict__ hb) {
  __shared__ __align__(16) float h_q[2][2][4][28];  // [buf][seq][quarter][25+pad]
  __shared__ int xl[2][512];                        // scan-order x indices
  int bid = blockIdx.x;
  int pair = bid >> 1, dir = bid & 1;
  int tid = threadIdx.x;
  int u = tid >> 2, q = tid & 3;
  const float* Whh = dir ? Whh_b : Whh_f;
  float* hdir = dir ? hb : hf;
  float* houtA = hdir + (size_t)(pair * 2) * 51200;
  float* houtB = hdir + (size_t)(pair * 2 + 1) * 51200;
  const int* xbA = x + (size_t)(pair * 2) * 512;
  const int* xbB = x + (size_t)(pair * 2 + 1) * 512;
  const int dirb = dir * 400;
  const int s0 = dir ? 511 : 0, sstep = dir ? -1 : 1;

  for (int i = tid; i < 512; i += 400) {
    xl[0][i] = xbA[s0 + sstep * i];
    xl[1][i] = xbB[s0 + sstep * i];
  }

  // Whh quarter fragments, packed: 13 v2f per gate row (tail {w24, 0})
  v2f w2[4][13];
#pragma unroll
  for (int g = 0; g < 4; ++g) {
    const float* pr = Whh + (size_t)(g * 100 + u) * 100 + q * 25;
#pragma unroll
    for (int k = 0; k < 12; ++k) w2[g][k] = v2f{pr[2 * k], pr[2 * k + 1]};
    w2[g][12] = v2f{pr[24], 0.f};
  }
  const int uq = u / 25, up = u - uq * 25;
  float* houtme = (q == 1) ? houtB : houtA;

  for (int i = tid; i < 448; i += 400) ((float*)h_q)[i] = 0.f;  // both bufs+pads
  float c = 0.f;
  __syncthreads();

  const float* ewq = EW + dirb + q * 100 + u;
  float pA0 = ewq[(size_t)xl[0][0] * 800];
  float pB0 = ewq[(size_t)xl[1][0] * 800];
  float pA1 = ewq[(size_t)xl[0][1] * 800];
  float pB1 = ewq[(size_t)xl[1][1] * 800];

  auto STEP = [&](int t, float& pA, float& pB) {
    int s = s0 + sstep * t;
    int cb = t & 1, nb = cb ^ 1;
    const float* hA = &h_q[cb][0][q][0];
    const float* hB = &h_q[cb][1][q][0];
    v2f ra[4], rb[4];
#pragma unroll
    for (int g = 0; g < 4; ++g) { ra[g] = v2f{0.f, 0.f}; rb[g] = v2f{0.f, 0.f}; }
#pragma unroll
    for (int m = 0; m < 6; ++m) {
      v4f a4 = *(const v4f*)(hA + 4 * m);
      v4f b4 = *(const v4f*)(hB + 4 * m);
      v2f alo = v2f{a4.x, a4.y}, ahi = v2f{a4.z, a4.w};
      v2f blo = v2f{b4.x, b4.y}, bhi = v2f{b4.z, b4.w};
#pragma unroll
      for (int g = 0; g < 4; ++g) {
        ra[g] += w2[g][2 * m] * alo;
        ra[g] += w2[g][2 * m + 1] * ahi;
        rb[g] += w2[g][2 * m] * blo;
        rb[g] += w2[g][2 * m + 1] * bhi;
      }
    }
    {
      v2f at = *(const v2f*)(hA + 24);  // element 25 is the zeroed pad
      v2f bt = *(const v2f*)(hB + 24);
#pragma unroll
      for (int g = 0; g < 4; ++g) { ra[g] += w2[g][12] * at; rb[g] += w2[g][12] * bt; }
    }

    float gate[4];
#pragma unroll
    for (int g = 0; g < 4; ++g) {
      float sa = ra[g].x + ra[g].y + ((q == g) ? pA : 0.0f);
      float sb = rb[g].x + rb[g].y + ((q == g) ? pB : 0.0f);
      float qa = qred(sa);
      float qb = qred(sb);
      gate[g] = (q & 1) ? qb : qa;
    }
    if (q < 2) {
      c = sigf(gate[1]) * c + sigf(gate[0]) * tanhf_(gate[2]);
      float h = sigf(gate[3]) * tanhf_(c);
      h_q[nb][q][uq][up] = h;
      houtme[(size_t)s * 100 + u] = h;
    }
    // reload this buffer for step t+2 (in flight ~1.8 steps)
    int i2 = min(t + 2, 511);
    pA = ewq[(size_t)xl[0][i2] * 800];
    pB = ewq[(size_t)xl[1][i2] * 800];
    __syncthreads();
  };

  for (int t = 0; t < 512; t += 2) {
    STEP(t, pA0, pB0);
    STEP(t + 1, pA1, pB1);
  }
}

// ---------------------------------------------------------------- emis ----
// em[row][v] = sum_d hcat[row][d] * M2[v][d] + c0[v]; 32 rows/block
__global__ __launch_bounds__(128) void emis_kernel(
    const float* __restrict__ hfB, const float* __restrict__ hbB,
    const float* __restrict__ M2g, const float* __restrict__ c0g,
    float* __restrict__ em) {
  __shared__ __align__(16) float hrow[32 * 204];
  __shared__ __align__(16) float M2l[4000];
  __shared__ float c0l[20];
  int tid = threadIdx.x;
  int row0 = blockIdx.x * 32;
  for (int i = tid; i < 800; i += 128) {
    int r = i / 25, q = i - r * 25;
    *(float4*)&hrow[r * 204 + q * 4] =
        *(const float4*)(hfB + (size_t)(row0 + r) * 100 + q * 4);
    *(float4*)&hrow[r * 204 + 100 + q * 4] =
        *(const float4*)(hbB + (size_t)(row0 + r) * 100 + q * 4);
  }
  for (int i = tid; i < 1000; i += 128) ((float4*)M2l)[i] = ((const float4*)M2g)[i];
  if (tid < 20) c0l[tid] = (tid < 19) ? c0g[tid] : 0.f;
  __syncthreads();

  int r = tid >> 2, q = tid & 3;
  int v0 = q * 5;
  float acc[5] = {0.f, 0.f, 0.f, 0.f, 0.f};
  for (int k = 0; k < 200; k += 4) {
    float4 h4 = *(const float4*)&hrow[r * 204 + k];
#pragma unroll
    for (int i = 0; i < 5; ++i) {
      float4 m4 = *(const float4*)&M2l[(v0 + i) * 200 + k];
      acc[i] += h4.x * m4.x + h4.y * m4.y + h4.z * m4.z + h4.w * m4.w;
    }
  }
  int nv = (q == 3) ? 4 : 5;
  for (int i = 0; i < nv; ++i)
    em[(size_t)(row0 + r) * 19 + v0 + i] = acc[i] + c0l[v0 + i];
}

// ----------------------------------------------------------------- crf ----
// one wave per batch element; log2 domain (native v_exp/v_log). BOS col and
// EOS row are annihilated by the -10000 mask (exp underflows to 0 in fp32
// exactly as in the reference), so the live recursion is 17x17. Alphas are
// broadcast lane0..16 -> all lanes via __shfl (no LDS, no per-step barrier).
__global__ __launch_bounds__(64) void crf_kernel(
    const float* __restrict__ em, const int* __restrict__ target,
    const float* __restrict__ T, float* __restrict__ res) {
  __shared__ float em_l[512 * 19];
  __shared__ float T_l[361];
  __shared__ int tgt_l[512];
  constexpr float LOG2E = 1.4426950408889634f;
  constexpr float LN2 = 0.6931471805599453f;
  int b = blockIdx.x, lane = threadIdx.x;
  const float* emsrc = em + (size_t)b * 512 * 19;
  for (int i = lane; i < 512 * 19; i += 64) em_l[i] = emsrc[i] * LOG2E;
  for (int i = lane; i < 361; i += 64) T_l[i] = T[i] * LOG2E;
  for (int i = lane; i < 512; i += 64) tgt_l[i] = target[b * 512 + i];
  __syncthreads();

  float sc = 0.f;
  for (int t = lane; t < 512; t += 64) {
    int tg = tgt_l[t];
    sc += em_l[t * 19 + tg];
    if (t < 511) sc += T_l[tg * 19 + tgt_l[t + 1]];
  }
#pragma unroll
  for (int off = 32; off >= 1; off >>= 1) sc += __shfl_xor(sc, off);

  int v = (lane < 17) ? lane : 0;
  float Tcol[17];
#pragma unroll
  for (int u = 0; u < 17; ++u) Tcol[u] = T_l[u * 19 + v];
  float a[17];
#pragma unroll
  for (int u = 0; u < 17; ++u) a[u] = T_l[BOS_ * 19 + u] + em_l[u];

  for (int t = 1; t < 512; ++t) {
    float xx[17];
#pragma unroll
    for (int u = 0; u < 17; ++u) xx[u] = a[u] + Tcol[u];
    float m = xx[0];
#pragma unroll
    for (int u = 1; u < 17; ++u) m = fmaxf(m, xx[u]);
    float s0 = 0.f, s1 = 0.f, s2 = 0.f, s3 = 0.f;
#pragma unroll
    for (int u = 0; u < 16; u += 4) {
      s0 += exp2f(xx[u] - m);
      s1 += exp2f(xx[u + 1] - m);
      s2 += exp2f(xx[u + 2] - m);
      s3 += exp2f(xx[u + 3] - m);
    }
    s0 += exp2f(xx[16] - m);
    float na = m + log2f((s0 + s1) + (s2 + s3)) + em_l[t * 19 + v];
#pragma unroll
    for (int u = 0; u < 17; ++u) a[u] = __shfl(na, u, 64);
  }

  float xx[17];
#pragma unroll
  for (int u = 0; u < 17; ++u) xx[u] = a[u] + T_l[u * 19 + EOS_];
  float m = xx[0];
#pragma unroll
  for (int u = 1; u < 17; ++u) m = fmaxf(m, xx[u]);
  float ssum = 0.f;
#pragma unroll
  for (int u = 0; u < 17; ++u) ssum += exp2f(xx[u] - m);
  float part = m + log2f(ssum);

  if (lane == 0) {
    float score = sc + T_l[BOS_ * 19 + tgt_l[0]] + T_l[tgt_l[511] * 19 + EOS_];
    res[b] = (score - part) * LN2;
  }
}

// ------------------------------------------------------------- final -----
__global__ void final_kernel(const float* __restrict__ res, float* __restrict__ out) {
  int lane = threadIdx.x;
  float s = 0.f;
  for (int i = lane; i < 256; i += 64) s += res[i];
#pragma unroll
  for (int off = 32; off >= 1; off >>= 1) s += __shfl_xor(s, off);
  if (lane == 0) out[0] = -s * (1.0f / 256.0f);
}

// ---------------------------------------------------------------------------
extern "C" void kernel_launch(void* const* d_in, const int* in_sizes, int n_in,
                              void* d_out, int out_size, void* d_ws, size_t ws_size,
                              hipStream_t stream) {
  const int*   x      = (const int*)d_in[0];
  const int*   target = (const int*)d_in[1];
  const float* emb    = (const float*)d_in[2];
  const float* Wih_f  = (const float*)d_in[3];
  const float* Whh_f  = (const float*)d_in[4];
  const float* bih_f  = (const float*)d_in[5];
  const float* bhh_f  = (const float*)d_in[6];
  const float* Wih_b  = (const float*)d_in[7];
  const float* Whh_b  = (const float*)d_in[8];
  const float* bih_b  = (const float*)d_in[9];
  const float* bhh_b  = (const float*)d_in[10];
  const float* W1     = (const float*)d_in[11];
  const float* b1     = (const float*)d_in[12];
  const float* W2     = (const float*)d_in[13];
  const float* b2     = (const float*)d_in[14];
  const float* trans  = (const float*)d_in[15];
  float* out = (float*)d_out;

  float* ws = (float*)d_ws;
  float* em      = ws;                          // BS*19          (~10 MB)
  float* M2      = em + (size_t)BS_ * 19;       // 4000
  float* c0      = M2 + 4000;                   // 64
  float* biasAll = c0 + 64;                     // 1024
  float* res     = biasAll + 1024;              // 256
  float* hfbuf   = res + 256;                   // BS*100         (~52 MB)
  float* hbbuf   = hfbuf + (size_t)BS_ * 100;   // BS*100         (~52 MB)
  float* EW      = hbbuf + (size_t)BS_ * 100;   // V*800          (~96 MB)

  prep_kernel<<<1, 256, 0, stream>>>(W1, b1, W2, b2, bih_f, bhh_f, bih_b, bhh_b,
                                     M2, c0, biasAll);
  ewbuild_kernel<<<dim3(10, (V_ + 63) / 64), 256, 0, stream>>>(emb, Wih_f, Wih_b,
                                                               biasAll, EW);
  scan_fused3_kernel<<<256, 400, 0, stream>>>(x, EW, Whh_f, Whh_b, hfbuf, hbbuf);
  emis_kernel<<<BS_ / 32, 128, 0, stream>>>(hfbuf, hbbuf, M2, c0, em);
  crf_kernel<<<B_, 64, 0, stream>>>(em, target, trans, res);
  final_kernel<<<1, 64, 0, stream>>>(res, out);
}